// Round 3
// baseline (30.034 us; speedup 1.0000x reference)
//
#include <hip/hip_runtime.h>

// Embedding gather: out[tok, :] = weights[x[tok], :]
// x: [65536] int32 in [0,256); weights: [256,512] f32; out: [65536,512] f32.
// Memory-bound: 128 MiB output write dominates (weights live in L2).
// Structure: fixed 16-iter unrolled grid-stride; hoist the 16 independent
// index loads so the 16 weight gathers issue without dependent-chain stalls;
// nontemporal stores for the write-once output stream.
// Note: __builtin_nontemporal_store needs a native clang vector type, not
// the HIP float4 struct — use ext_vector_type(4).

typedef float f32x4 __attribute__((ext_vector_type(4)));

#define BLOCK 256
#define GRID  2048
#define ITERS 16   // 2048*256*16 = 8,388,608 = 65536 tokens * 128 f32x4

__global__ __launch_bounds__(BLOCK) void emb_gather_kernel(
        const int* __restrict__ x,
        const f32x4* __restrict__ w,
        f32x4* __restrict__ out,
        int total_vec4) {
    const int stride = GRID * BLOCK;
    const int i0 = blockIdx.x * BLOCK + threadIdx.x;

    // Hoist index loads: all 16 are independent (tok = i>>7 is wave-uniform,
    // lanes broadcast from L1). Breaks the x->w dependent chain.
    int toks[ITERS];
#pragma unroll
    for (int k = 0; k < ITERS; ++k) {
        const int i = i0 + k * stride;
        toks[k] = (i < total_vec4) ? x[i >> 7] : 0;
    }

#pragma unroll
    for (int k = 0; k < ITERS; ++k) {
        const int i = i0 + k * stride;
        if (i < total_vec4) {
            const f32x4 v = w[(toks[k] << 7) + (i & 127)];   // L2-resident gather
            __builtin_nontemporal_store(v, &out[i]);          // write-once stream
        }
    }
}

extern "C" void kernel_launch(void* const* d_in, const int* in_sizes, int n_in,
                              void* d_out, int out_size, void* d_ws, size_t ws_size,
                              hipStream_t stream) {
    const int*   x = (const int*)d_in[0];       // [8, 8192] int32
    const f32x4* w = (const f32x4*)d_in[1];     // [256, 512] f32 as [256,128] f32x4
    f32x4*     out = (f32x4*)d_out;             // [65536, 512] f32 as f32x4

    const int n_tokens   = in_sizes[0];         // 65536
    const int total_vec4 = n_tokens * 128;

    emb_gather_kernel<<<GRID, BLOCK, 0, stream>>>(x, w, out, total_vec4);
}

// Round 4
// 27.855 us; speedup vs baseline: 1.0782x; 1.0782x over previous
//
#include <hip/hip_runtime.h>

// Embedding gather: out[tok, :] = weights[x[tok], :]
// x: [65536] int32 in [0,256); weights: [256,512] f32; out: [65536,512] f32.
// Memory-bound: 128 MiB output write dominates (weights are L2/L3-resident).
//
// Round-3 post-mortem: nontemporal stores + 16-deep index hoist REGRESSED
// (26.1 -> 30.0 us). nt (L2-bypass) hurts write efficiency on gfx950; ILP
// hoist useless at full occupancy. This version: plain b128 stores, exact
// division (no bounds branch), modest 8-iter unroll, grid=4096 for full
// occupancy with shorter per-block work.

typedef float f32x4 __attribute__((ext_vector_type(4)));

#define BLOCK 256
#define GRID  4096
#define ITERS 8   // 4096*256*8 = 8,388,608 = 65536 tokens * 128 f32x4 (exact)

__global__ __launch_bounds__(BLOCK) void emb_gather_kernel(
        const int* __restrict__ x,
        const f32x4* __restrict__ w,
        f32x4* __restrict__ out) {
    const int stride = GRID * BLOCK;
    int i = blockIdx.x * BLOCK + threadIdx.x;

#pragma unroll
    for (int k = 0; k < ITERS; ++k, i += stride) {
        const int tok = x[i >> 7];                 // wave-uniform span, L1 broadcast
        const f32x4 v = w[(tok << 7) + (i & 127)]; // L2-resident 16B gather
        out[i] = v;                                // coalesced b128 store
    }
}

extern "C" void kernel_launch(void* const* d_in, const int* in_sizes, int n_in,
                              void* d_out, int out_size, void* d_ws, size_t ws_size,
                              hipStream_t stream) {
    const int*   x = (const int*)d_in[0];       // [8, 8192] int32
    const f32x4* w = (const f32x4*)d_in[1];     // [256, 512] f32 as [256,128] f32x4
    f32x4*     out = (f32x4*)d_out;             // [65536, 512] f32 as f32x4

    // Shapes are fixed by the harness (65536 tokens); grid*block*iters matches
    // total_vec4 exactly, so no bounds checks needed.
    emb_gather_kernel<<<GRID, BLOCK, 0, stream>>>(x, w, out);
}

// Round 5
// 26.230 us; speedup vs baseline: 1.1450x; 1.0620x over previous
//
#include <hip/hip_runtime.h>

// Embedding gather: out[tok, :] = weights[x[tok], :]
// x: [8*8192] int32 in [0,256); weights: [256,512] f32; out: [8*8192, 512] f32.
// Row = 512 f32 = 128 float4. Memory-bound: 128 MiB output write dominates.
//
// Best-known structure (Round 1, 26.07 us). Experiments that LOST:
//  - nontemporal stores + 16-deep index hoist: 30.0 us (nt hurts on gfx950)
//  - exact-division 8x unroll @ grid=4096:      27.9 us
// At ~8 VGPR the kernel runs 32 waves/CU; TLP hides gather latency, so the
// simple dependent-chain grid-stride loop paces stores best. Floor is the
// 128 MiB mandatory write: ~20 us @ 6.7 TB/s + ~5 us launch/graph overhead.
__global__ void emb_gather_kernel(const int* __restrict__ x,
                                  const float4* __restrict__ w,
                                  float4* __restrict__ out,
                                  int total_vec4 /* n_tokens * 128 */) {
    const int stride = gridDim.x * blockDim.x;
    for (int i = blockIdx.x * blockDim.x + threadIdx.x; i < total_vec4; i += stride) {
        const int tok = i >> 7;        // 128 float4 per token row
        const int col = i & 127;
        const int idx = x[tok];        // wave-uniform within 64-lane span (L1 hit)
        out[i] = w[(idx << 7) + col];  // weights row in float4 units (512/4 = 128)
    }
}

extern "C" void kernel_launch(void* const* d_in, const int* in_sizes, int n_in,
                              void* d_out, int out_size, void* d_ws, size_t ws_size,
                              hipStream_t stream) {
    const int*    x = (const int*)d_in[0];      // [8, 8192] int32
    const float4* w = (const float4*)d_in[1];   // [256, 512] f32 viewed as [256,128] float4
    float4*     out = (float4*)d_out;           // [65536, 512] f32 viewed as float4

    const int n_tokens   = in_sizes[0];         // 65536
    const int total_vec4 = n_tokens * 128;      // 8,388,608 float4 stores

    const int block = 256;
    const int grid  = 2048;                     // grid-stride covers the rest
    emb_gather_kernel<<<grid, block, 0, stream>>>(x, w, out, total_vec4);
}